// Round 9
// baseline (770.131 us; speedup 1.0000x reference)
//
#include <hip/hip_runtime.h>
#include <hip/hip_bf16.h>

#define Sn    2048
#define HIDn  2048
#define HQn   16
#define HKVn  2
#define HDn   128
#define Gn    8
#define CSn   128
#define Ncn   16
#define NBLK  8
#define WINn  16
#define SCALEf 0.08838834764831845f   // 128^-0.5
#define NEGf  (-1.0e9f)
#define ALPHAf 0.8f
#define MIXLf  0.5f
#define EPSGAP 2.0e-3f
#define FLAGCAP 2040

typedef __attribute__((ext_vector_type(8))) short short8;   // 8 bf16 = 4 VGPRs
typedef __attribute__((ext_vector_type(4))) short short4v;
typedef __attribute__((ext_vector_type(4))) float f32x4;
typedef __attribute__((ext_vector_type(4))) int int4v;

static __device__ __forceinline__ short f2bf(float x) {
    union { float f; unsigned u; } v; v.f = x;
    unsigned r = v.u + 0x7fffu + ((v.u >> 16) & 1u);
    return (short)(r >> 16);
}
static __device__ __forceinline__ float bf2f(short b) {
    union { float f; unsigned u; } v; v.u = ((unsigned)(unsigned short)b) << 16;
    return v.f;
}

// ---------------- fp32 GEMM (fallback path only) ----------------
__global__ void gemm64(const float* __restrict__ A, const float* __restrict__ W,
                       const float* __restrict__ bias, float* __restrict__ C,
                       int M, int N, int K) {
    __shared__ float As[16][65];
    __shared__ float Bs[16][65];
    const int tid = threadIdx.x;
    const int tx = tid & 15, ty = tid >> 4;
    const int m0 = blockIdx.y * 64, n0 = blockIdx.x * 64;
    float acc[4][4] = {};
    for (int k0 = 0; k0 < K; k0 += 16) {
#pragma unroll
        for (int r = 0; r < 4; ++r) {
            int flat = tid + 256 * r;
            int am = flat >> 4, ak = flat & 15;
            As[ak][am] = A[(size_t)(m0 + am) * K + k0 + ak];
            int bk = flat >> 6, bn = flat & 63;
            Bs[bk][bn] = W[(size_t)(k0 + bk) * N + n0 + bn];
        }
        __syncthreads();
#pragma unroll
        for (int kk = 0; kk < 16; ++kk) {
            float a[4], b[4];
#pragma unroll
            for (int i = 0; i < 4; ++i) a[i] = As[kk][ty * 4 + i];
#pragma unroll
            for (int j = 0; j < 4; ++j) b[j] = Bs[kk][tx * 4 + j];
#pragma unroll
            for (int i = 0; i < 4; ++i)
#pragma unroll
                for (int j = 0; j < 4; ++j) acc[i][j] += a[i] * b[j];
        }
        __syncthreads();
    }
#pragma unroll
    for (int i = 0; i < 4; ++i)
#pragma unroll
        for (int j = 0; j < 4; ++j) {
            int m = m0 + ty * 4 + i, n = n0 + tx * 4 + j;
            C[(size_t)m * N + n] = acc[i][j] + (bias ? bias[n] : 0.0f);
        }
}

// ---------------- split-K fp32 GEMM for K projection (M=2048,N=256,K=2048) ----
__global__ __launch_bounds__(256) void kproj_splitk(
        const float* __restrict__ A, const float* __restrict__ W,
        const float* __restrict__ bias, float* __restrict__ C,
        int M, int N, int K, int Ks) {
    __shared__ float As[16][68];   // [k][m]
    __shared__ float Bs[16][68];   // [k][n]
    const int tid = threadIdx.x;
    const int tx = tid & 15, ty = tid >> 4;
    const int m0 = blockIdx.y * 64, n0 = blockIdx.x * 64;
    const int kbase = blockIdx.z * Ks;
    const int am = tid >> 2, ac = tid & 3;     // A: row am (64), float4 seg ac (4)
    const int bk = tid >> 4, bc = tid & 15;    // B: row bk (16), float4 seg bc (16)
    float acc[4][4] = {};
    for (int k0 = kbase; k0 < kbase + Ks; k0 += 16) {
        float4 av = *(const float4*)&A[(size_t)(m0 + am) * K + k0 + ac * 4];
        As[ac * 4 + 0][am] = av.x;
        As[ac * 4 + 1][am] = av.y;
        As[ac * 4 + 2][am] = av.z;
        As[ac * 4 + 3][am] = av.w;
        *(float4*)&Bs[bk][bc * 4] =
            *(const float4*)&W[(size_t)(k0 + bk) * N + n0 + bc * 4];
        __syncthreads();
#pragma unroll
        for (int kk = 0; kk < 16; ++kk) {
            float4 a4 = *(const float4*)&As[kk][ty * 4];
            float4 b4 = *(const float4*)&Bs[kk][tx * 4];
            float a[4] = {a4.x, a4.y, a4.z, a4.w};
            float b[4] = {b4.x, b4.y, b4.z, b4.w};
#pragma unroll
            for (int i = 0; i < 4; ++i)
#pragma unroll
                for (int j = 0; j < 4; ++j) acc[i][j] += a[i] * b[j];
        }
        __syncthreads();
    }
    const bool addb = (blockIdx.z == 0) && (bias != nullptr);
#pragma unroll
    for (int i = 0; i < 4; ++i)
#pragma unroll
        for (int j = 0; j < 4; ++j) {
            int m = m0 + ty * 4 + i, n = n0 + tx * 4 + j;
            float v = acc[i][j] + (addb ? bias[n] : 0.0f);
            atomicAdd(&C[(size_t)m * N + n], v);
        }
}

// ---------------- W[K][N] fp32 -> Wt[N][K] bf16 hi (+lo) ----------------
__global__ void trans_split(const float* __restrict__ W, short* __restrict__ Whi,
                            short* __restrict__ Wlo, int K, int N) {
    __shared__ float tl[32][33];
    const int k0 = blockIdx.y * 32, n0 = blockIdx.x * 32;
    const int c = threadIdx.x & 31, r8 = threadIdx.x >> 5;
#pragma unroll
    for (int it = 0; it < 4; ++it) {
        int r = r8 + it * 8;
        tl[r][c] = W[(size_t)(k0 + r) * N + n0 + c];
    }
    __syncthreads();
#pragma unroll
    for (int it = 0; it < 4; ++it) {
        int r = r8 + it * 8;
        float x = tl[c][r];                      // = W[k0+c][n0+r]
        short hi = f2bf(x);
        Whi[(size_t)(n0 + r) * K + k0 + c] = hi;
        if (Wlo) Wlo[(size_t)(n0 + r) * K + k0 + c] = f2bf(x - bf2f(hi));
    }
}

// ---------------- hs fp32 -> bf16 hi/lo (once, removes per-tile reconversion) --
__global__ void split_hs(const float* __restrict__ hs, short* __restrict__ hi,
                         short* __restrict__ lo) {
    int idx = blockIdx.x * blockDim.x + threadIdx.x;   // S*HID/4 float4s
    float4 v = ((const float4*)hs)[idx];
    short4v h, l;
    float x[4] = {v.x, v.y, v.z, v.w};
#pragma unroll
    for (int i = 0; i < 4; ++i) {
        short hh = f2bf(x[i]);
        h[i] = hh;
        l[i] = f2bf(x[i] - bf2f(hh));
    }
    ((short4v*)hi)[idx] = h;
    ((short4v*)lo)[idx] = l;
}

// ---------------- MFMA GEMM: C[M,N] = A[M,K] @ B + bias ----------------
// B transposed bf16 [N][K]. AMODE: 0 = A bf16; 1 = A fp32 split bf16x3 on the
// fly; 2 = A fp32 rounded to bf16 single; 3 = A pre-split bf16 hi/lo (Av=hi,
// Alo2=lo). VOUT: epilogue writes vtb bf16 [kv][c][d][j]. SK: K sliced across
// blockIdx.z, fp32 atomicAdd epilogue (C pre-zeroed), bias added by z==0.
template <int AMODE, bool VOUT, bool SK>
__global__ __launch_bounds__(256) void gemm_mfma(
        const void* __restrict__ Av, const short* __restrict__ Alo2,
        const short* __restrict__ Bhi, const short* __restrict__ Blo,
        const float* __restrict__ bias, float* __restrict__ C,
        short* __restrict__ vout, int M, int N, int K) {
    constexpr bool DUAL = (AMODE == 1 || AMODE == 3);
    __shared__ short Ahs[128][40];
    __shared__ short Bhs[128][40];
    __shared__ short Als[DUAL ? 128 : 1][40];
    __shared__ short Bls[DUAL ? 128 : 1][40];
    const int tid = threadIdx.x;
    const int w = tid >> 6, lane = tid & 63, nl = lane & 15, quad = lane >> 4;
    const int wm = w >> 1, wn = w & 1;
    const int m0 = blockIdx.y * 128, n0 = blockIdx.x * 128;
    const int srow = tid >> 1, sseg = tid & 1;
    f32x4 acc[4][4];
#pragma unroll
    for (int i = 0; i < 4; ++i)
#pragma unroll
        for (int j = 0; j < 4; ++j) acc[i][j] = (f32x4){0.f, 0.f, 0.f, 0.f};

    int kbeg = 0, kend = K;
    if (SK) { int Ks = K / gridDim.z; kbeg = blockIdx.z * Ks; kend = kbeg + Ks; }

    for (int k0 = kbeg; k0 < kend; k0 += 32) {
        if (AMODE == 1 || AMODE == 2) {
            const float* A = (const float*)Av;
            const float* ap = A + (size_t)(m0 + srow) * K + k0 + sseg * 16;
            short8 hi0, hi1, lo0, lo1;
#pragma unroll
            for (int i = 0; i < 8; ++i) {
                float x = ap[i];
                short h = f2bf(x);
                hi0[i] = h; if (AMODE == 1) lo0[i] = f2bf(x - bf2f(h));
            }
#pragma unroll
            for (int i = 0; i < 8; ++i) {
                float x = ap[8 + i];
                short h = f2bf(x);
                hi1[i] = h; if (AMODE == 1) lo1[i] = f2bf(x - bf2f(h));
            }
            *(short8*)&Ahs[srow][sseg * 16] = hi0;
            *(short8*)&Ahs[srow][sseg * 16 + 8] = hi1;
            if (AMODE == 1) {
                *(short8*)&Als[srow][sseg * 16] = lo0;
                *(short8*)&Als[srow][sseg * 16 + 8] = lo1;
            }
        } else {
            const short* A = (const short*)Av;
            const short* ap = A + (size_t)(m0 + srow) * K + k0 + sseg * 16;
            *(short8*)&Ahs[srow][sseg * 16]     = *(const short8*)(ap);
            *(short8*)&Ahs[srow][sseg * 16 + 8] = *(const short8*)(ap + 8);
            if (AMODE == 3) {
                const short* al = Alo2 + (size_t)(m0 + srow) * K + k0 + sseg * 16;
                *(short8*)&Als[srow][sseg * 16]     = *(const short8*)(al);
                *(short8*)&Als[srow][sseg * 16 + 8] = *(const short8*)(al + 8);
            }
        }
        {
            const short* bh = Bhi + (size_t)(n0 + srow) * K + k0 + sseg * 16;
            *(short8*)&Bhs[srow][sseg * 16]     = *(const short8*)(bh);
            *(short8*)&Bhs[srow][sseg * 16 + 8] = *(const short8*)(bh + 8);
        }
        if (DUAL) {
            const short* bl = Blo + (size_t)(n0 + srow) * K + k0 + sseg * 16;
            *(short8*)&Bls[srow][sseg * 16]     = *(const short8*)(bl);
            *(short8*)&Bls[srow][sseg * 16 + 8] = *(const short8*)(bl + 8);
        }
        __syncthreads();
        short8 af[4], bf_[4], al[4], bl_[4];
#pragma unroll
        for (int tm = 0; tm < 4; ++tm)
            af[tm] = *(const short8*)&Ahs[wm * 64 + tm * 16 + nl][quad * 8];
#pragma unroll
        for (int tn = 0; tn < 4; ++tn)
            bf_[tn] = *(const short8*)&Bhs[wn * 64 + tn * 16 + nl][quad * 8];
        if (DUAL) {
#pragma unroll
            for (int tm = 0; tm < 4; ++tm)
                al[tm] = *(const short8*)&Als[wm * 64 + tm * 16 + nl][quad * 8];
#pragma unroll
            for (int tn = 0; tn < 4; ++tn)
                bl_[tn] = *(const short8*)&Bls[wn * 64 + tn * 16 + nl][quad * 8];
        }
#pragma unroll
        for (int tm = 0; tm < 4; ++tm)
#pragma unroll
            for (int tn = 0; tn < 4; ++tn) {
                acc[tm][tn] = __builtin_amdgcn_mfma_f32_16x16x32_bf16(af[tm], bf_[tn], acc[tm][tn], 0, 0, 0);
                if (DUAL) {
                    acc[tm][tn] = __builtin_amdgcn_mfma_f32_16x16x32_bf16(af[tm], bl_[tn], acc[tm][tn], 0, 0, 0);
                    acc[tm][tn] = __builtin_amdgcn_mfma_f32_16x16x32_bf16(al[tm], bf_[tn], acc[tm][tn], 0, 0, 0);
                }
            }
        __syncthreads();
    }
    const bool addb = (bias != nullptr) && (!SK || blockIdx.z == 0);
#pragma unroll
    for (int tm = 0; tm < 4; ++tm)
#pragma unroll
        for (int tn = 0; tn < 4; ++tn)
#pragma unroll
            for (int r = 0; r < 4; ++r) {
                int m = m0 + wm * 64 + tm * 16 + quad * 4 + r;
                int n = n0 + wn * 64 + tn * 16 + nl;
                float v = acc[tm][tn][r] + (addb ? bias[n] : 0.0f);
                if (VOUT) {
                    int kv = n >> 7, d = n & 127, cc = m >> 7, j = m & 127;
                    vout[(((size_t)kv * Ncn + cc) * 128 + d) * 128 + j] = f2bf(v);
                } else if (SK) {
                    atomicAdd(&C[(size_t)m * N + n], v);
                } else {
                    C[(size_t)m * N + n] = v;
                }
            }
}

// ---------------- RoPE in-place on q and k; k also -> bf16 ----------------
__global__ void rope_kernel(float* __restrict__ q, float* __restrict__ k,
                            const float* __restrict__ cosb, const float* __restrict__ sinb,
                            short* __restrict__ kb) {
    int idx = blockIdx.x * blockDim.x + threadIdx.x;   // S*18*64
    int s = idx / (18 * 64);
    int r = idx % (18 * 64);
    int head = r >> 6;
    int d = r & 63;
    float c0 = cosb[s * 128 + d], c1 = cosb[s * 128 + d + 64];
    float s0 = sinb[s * 128 + d], s1 = sinb[s * 128 + d + 64];
    if (head < 16) {
        float* base = q + (size_t)s * 2048 + head * 128;
        float x0 = base[d], x1 = base[d + 64];
        base[d]      = x0 * c0 - x1 * s0;
        base[d + 64] = x1 * c1 + x0 * s1;
    } else {
        int kv = head - 16;
        float* base = k + (size_t)s * 256 + kv * 128;
        float x0 = base[d], x1 = base[d + 64];
        float y0 = x0 * c0 - x1 * s0;
        float y1 = x1 * c1 + x0 * s1;
        base[d] = y0; base[d + 64] = y1;
        short* ko = kb + ((size_t)kv * Sn + s) * 128;
        ko[d] = f2bf(y0); ko[d + 64] = f2bf(y1);
    }
}

// ---------------- V (fp32) -> bf16, transposed per chunk ----------
__global__ void conv_v(const float* __restrict__ v, short* __restrict__ vtb) {
    int idx = blockIdx.x * blockDim.x + threadIdx.x;   // S*256
    int pos = idx >> 8;
    int rem = idx & 255;
    int kv = rem >> 7, d = rem & 127;
    float val = v[(size_t)pos * 256 + kv * 128 + d];
    int c = pos >> 7, j = pos & 127;
    vtb[(((size_t)kv * Ncn + c) * 128 + d) * 128 + j] = f2bf(val);
}

// ---------------- per-chunk K stats (512 thr: 4-way row split + LDS reduce) ----
__global__ void chunk_stats(const float* __restrict__ k, float* __restrict__ kcm,
                            float* __restrict__ kcx, int* __restrict__ flags) {
    if (blockIdx.x == 0 && threadIdx.x == 0) flags[0] = 0;
    int c = blockIdx.x & 15, kv = blockIdx.x >> 4;
    int d = threadIdx.x & 127, part = threadIdx.x >> 7;   // 4 parts x 32 rows
    float sum = 0.f, mx = -INFINITY;
    for (int j = part * 32; j < part * 32 + 32; ++j) {
        float v = k[(size_t)(c * 128 + j) * 256 + kv * 128 + d];
        sum += v; mx = fmaxf(mx, v);
    }
    __shared__ float ssum[4][128];
    __shared__ float smax[4][128];
    ssum[part][d] = sum; smax[part][d] = mx;
    __syncthreads();
    if (threadIdx.x < 128) {
        float s = ssum[0][d] + ssum[1][d] + ssum[2][d] + ssum[3][d];
        float m = fmaxf(fmaxf(smax[0][d], smax[1][d]), fmaxf(smax[2][d], smax[3][d]));
        kcm[(kv * 16 + c) * 128 + d] = s * (1.0f / 128.0f);
        kcx[(kv * 16 + c) * 128 + d] = m;
    }
}

// ---------------- block scores + top-8 -> chunk mask; flag genuine near-ties ----
__global__ void block_scores(const float* __restrict__ q, const float* __restrict__ kcm,
                             const float* __restrict__ kcx, unsigned int* __restrict__ mask32,
                             int* __restrict__ flags) {
    int qpos = blockIdx.x, kv = blockIdx.y;
    int t = threadIdx.x;          // 128: t = c*8 + g
    int c = t >> 3, g = t & 7;
    int h = kv * 8 + g;
    const float* qr = q + (size_t)qpos * 2048 + h * 128;
    const float* km = kcm + (kv * 16 + c) * 128;
    const float* kx = kcx + (kv * 16 + c) * 128;
    float dm = 0.f, dx = 0.f;
#pragma unroll 4
    for (int d = 0; d < 128; ++d) { float qv = qr[d]; dm += qv * km[d]; dx += qv * kx[d]; }
    float sg = (MIXLf * dm + (1.0f - MIXLf) * dx) * SCALEf;
    __shared__ float sh[16][8];
    __shared__ float vals[16];
    sh[c][g] = sg;
    __syncthreads();
    if (t < 16) {
        float mean = 0.f, mxv = -INFINITY;
#pragma unroll
        for (int gg = 0; gg < 8; ++gg) { mean += sh[t][gg]; mxv = fmaxf(mxv, sh[t][gg]); }
        mean *= 0.125f;
        float v = ALPHAf * mean + (1.0f - ALPHAf) * mxv;
        if (t * 128 > qpos) v = NEGf;
        vals[t] = v;
    }
    __syncthreads();
    if (t == 0) {
        unsigned int bits = 0;
        bool taken[16] = {};
        float v8 = -INFINITY;
        for (int it = 0; it < NBLK; ++it) {
            int best = 0; float bv = -INFINITY;
            for (int cc = 0; cc < 16; ++cc)
                if (!taken[cc] && vals[cc] > bv) { bv = vals[cc]; best = cc; }
            taken[best] = true;
            bits |= (1u << best);
            v8 = bv;
        }
        float v9 = -INFINITY;
        for (int cc = 0; cc < 16; ++cc)
            if (!taken[cc] && vals[cc] > v9) v9 = vals[cc];
        int lastc = qpos >> 7;
        unsigned int causal_bits = (1u << (lastc + 1)) - 1u;
        mask32[kv * 2048 + qpos] = bits & causal_bits;
        if (v9 > -0.5e9f && v8 - v9 < EPSGAP) {
            int idx = atomicAdd(flags, 1);
            if (idx < FLAGCAP) flags[1 + idx] = (kv << 16) | qpos;
        }
    }
}

// ---------------- exact fp32 q for flagged rows (parallel) ----------------
__global__ __launch_bounds__(256) void fixup_q(
        const float* __restrict__ hs, const float* __restrict__ Wq,
        const float* __restrict__ bq, const float* __restrict__ cosb,
        const float* __restrict__ sinb, const int* __restrict__ flags,
        float* __restrict__ qfix) {
    int cnt = flags[0]; if (cnt > FLAGCAP) cnt = FLAGCAP;
    const int items = cnt * 8;
    const int tid = threadIdx.x;
    __shared__ float hssh[2048];
    __shared__ float part[2][128];
    __shared__ float qrow[128];
    for (int item = blockIdx.x; item < items; item += gridDim.x) {
        int i = item >> 3, g = item & 7;
        int e = flags[1 + i];
        int kv = e >> 16, qpos = e & 0xffff;
        for (int j = tid; j < 2048; j += 256) hssh[j] = hs[(size_t)qpos * 2048 + j];
        __syncthreads();
        int d = tid & 127, half = tid >> 7;
        int col = (kv * 8 + g) * 128 + d;
        float s0 = 0.f, s1 = 0.f, s2 = 0.f, s3 = 0.f;
        const float* wp = Wq + (size_t)(half * 1024) * 2048 + col;
        const float* hp = hssh + half * 1024;
        for (int k = 0; k < 1024; k += 4) {
            s0 += hp[k + 0] * wp[(size_t)(k + 0) * 2048];
            s1 += hp[k + 1] * wp[(size_t)(k + 1) * 2048];
            s2 += hp[k + 2] * wp[(size_t)(k + 2) * 2048];
            s3 += hp[k + 3] * wp[(size_t)(k + 3) * 2048];
        }
        part[half][d] = (s0 + s1) + (s2 + s3);
        __syncthreads();
        if (tid < 128) qrow[tid] = part[0][tid] + part[1][tid] + bq[col];
        __syncthreads();
        if (tid < 64) {
            int dd = tid;
            float c0 = cosb[qpos * 128 + dd], c1 = cosb[qpos * 128 + dd + 64];
            float s0_ = sinb[qpos * 128 + dd], s1_ = sinb[qpos * 128 + dd + 64];
            float x0 = qrow[dd], x1 = qrow[dd + 64];
            qfix[(size_t)i * 1024 + g * 128 + dd]      = x0 * c0 - x1 * s0_;
            qfix[(size_t)i * 1024 + g * 128 + dd + 64] = x1 * c1 + x0 * s1_;
        }
        __syncthreads();
    }
}

// ---------------- redo top-8 for flagged rows from exact q ----------------
__global__ void fixup_sel(const float* __restrict__ qfix, const float* __restrict__ kcm,
                          const float* __restrict__ kcx, const int* __restrict__ flags,
                          unsigned int* __restrict__ mask32) {
    int cnt = flags[0]; if (cnt > FLAGCAP) cnt = FLAGCAP;
    int i = blockIdx.x;
    if (i >= cnt) return;
    int e = flags[1 + i];
    int kv = e >> 16, qpos = e & 0xffff;
    int t = threadIdx.x;
    int c = t >> 3, g = t & 7;
    const float* qr = qfix + (size_t)i * 1024 + g * 128;
    const float* km = kcm + (kv * 16 + c) * 128;
    const float* kx = kcx + (kv * 16 + c) * 128;
    float dm = 0.f, dx = 0.f;
#pragma unroll 4
    for (int d = 0; d < 128; ++d) { float qv = qr[d]; dm += qv * km[d]; dx += qv * kx[d]; }
    float sg = (MIXLf * dm + (1.0f - MIXLf) * dx) * SCALEf;
    __shared__ float sh[16][8];
    __shared__ float vals[16];
    sh[c][g] = sg;
    __syncthreads();
    if (t < 16) {
        float mean = 0.f, mxv = -INFINITY;
#pragma unroll
        for (int gg = 0; gg < 8; ++gg) { mean += sh[t][gg]; mxv = fmaxf(mxv, sh[t][gg]); }
        mean *= 0.125f;
        float v = ALPHAf * mean + (1.0f - ALPHAf) * mxv;
        if (t * 128 > qpos) v = NEGf;
        vals[t] = v;
    }
    __syncthreads();
    if (t == 0) {
        unsigned int bits = 0;
        bool taken[16] = {};
        for (int it = 0; it < NBLK; ++it) {
            int best = 0; float bv = -INFINITY;
            for (int cc = 0; cc < 16; ++cc)
                if (!taken[cc] && vals[cc] > bv) { bv = vals[cc]; best = cc; }
            taken[best] = true;
            bits |= (1u << best);
        }
        int lastc = qpos >> 7;
        unsigned int causal_bits = (1u << (lastc + 1)) - 1u;
        mask32[kv * 2048 + qpos] = bits & causal_bits;
    }
}

// ---------------- MFMA flash attention (key-slice split, swapped QK) ----------
// Block = 16 rows x head; 4 waves; wave w owns keys [32w, 32w+32).
// QK computed SWAPPED: mfma(A=K, B=Q) -> C[key][q]: lane holds q-row (lane&15)
// and 4 keys per reg. Row-max = 7-op register fmax tree + 2 shuffles (was 16);
// per-thread l accumulates in-register across chunks under the globally-synced
// per-row max (all waves apply identical fac sequences -> partials sum at the
// end). ONE barrier per chunk (Mb exchange only). Mb/Lb are [16][4] float4-
// readable. Same exact online-softmax algebra as the verified round-8 kernel.
__global__ __launch_bounds__(256, 2) void attn_mfma(
        float* __restrict__ qbuf, const short* __restrict__ kb,
        const short* __restrict__ vtb, const unsigned int* __restrict__ mask32,
        const int* __restrict__ am, short* __restrict__ ab) {
    __shared__ short Psh[4][16][40];
    __shared__ float Mb[16][4];       // [row][wave] per-chunk partial max
    __shared__ float Lb[16][4];       // [row][wave] final partial sums
    __shared__ float Ob[8][16][17];
    const int tid = threadIdx.x;
    const int w = tid >> 6, lane = tid & 63;
    const int nl = lane & 15, quad = lane >> 4;
    const int h = blockIdx.y, kv = h >> 3;
    const int par = w;
    const int r0 = ((int)gridDim.x - 1 - (int)blockIdx.x) * 16;

    const int mypos = r0 + nl;                       // this thread's softmax row
    const unsigned rbrow = mask32[kv * Sn + mypos];

    unsigned bits = mask32[kv * Sn + r0 + nl];
#pragma unroll
    for (int off = 1; off < 16; off <<= 1) bits |= __shfl_xor(bits, off, 64);
    int wl = (r0 >= 15) ? ((r0 - 15) >> 7) : 0;
    int wh = (r0 + 15) >> 7;
    for (int c = wl; c <= wh; ++c) bits |= (1u << c);
    const int cmw = (r0 + 15) >> 7;
    bits &= (1u << (cmw + 1)) - 1u;

    short8 qf[4];
    const float* qrow = qbuf + (size_t)(r0 + nl) * 2048 + h * 128;
#pragma unroll
    for (int ks = 0; ks < 4; ++ks) {
        float4 a = *(const float4*)(qrow + ks * 32 + quad * 8);
        float4 b = *(const float4*)(qrow + ks * 32 + quad * 8 + 4);
        short8 v;
        v[0] = f2bf(a.x); v[1] = f2bf(a.y); v[2] = f2bf(a.z); v[3] = f2bf(a.w);
        v[4] = f2bf(b.x); v[5] = f2bf(b.y); v[6] = f2bf(b.z); v[7] = f2bf(b.w);
        qf[ks] = v;
    }

    f32x4 oacc[8];
#pragma unroll
    for (int dt = 0; dt < 8; ++dt) oacc[dt] = (f32x4){0.f, 0.f, 0.f, 0.f};
    float m_nl = -INFINITY;                          // running max, row nl
    float m_acc[4] = {-INFINITY, -INFINITY, -INFINITY, -INFINITY}; // rows quad*4+r
    float l_t = 0.f;                                 // per-thread partial sum (row nl)

    unsigned remb = bits;
    while (remb) {
        const int c = __builtin_ctz(remb);
        remb &= remb - 1;
        const short* kcbase = kb + ((size_t)kv * Sn + c * 128) * 128;
        // ---- K loads: this wave's 2 t-tiles (32 keys) x 4 hd-slices ----
        short8 kf[2][4];
#pragma unroll
        for (int tt = 0; tt < 2; ++tt) {
            const short* krow = kcbase + (w * 32 + tt * 16 + nl) * 128;
#pragma unroll
            for (int ks = 0; ks < 4; ++ks)
                kf[tt][ks] = *(const short8*)(krow + ks * 32 + quad * 8);
        }
        int4v amv[2];
#pragma unroll
        for (int tt = 0; tt < 2; ++tt)
            amv[tt] = *(const int4v*)&am[c * 128 + w * 32 + tt * 16 + quad * 4];
        // ---- QK MFMAs SWAPPED: C[key][q], lane holds q-row nl, keys quad*4+r
        f32x4 sacc[2];
#pragma unroll
        for (int tt = 0; tt < 2; ++tt) {
            f32x4 a = (f32x4){0.f, 0.f, 0.f, 0.f};
#pragma unroll
            for (int ks = 0; ks < 4; ++ks)
                a = __builtin_amdgcn_mfma_f32_16x16x32_bf16(kf[tt][ks], qf[ks], a, 0, 0, 0);
            sacc[tt] = a;
        }
        __builtin_amdgcn_sched_barrier(0);
        // ---- V loads: 8 d-tiles x this wave's key-slice ----
        short8 vf[8];
        const short* vcbase = vtb + (((size_t)kv * Ncn + c) * 128) * 128;
#pragma unroll
        for (int dt = 0; dt < 8; ++dt)
            vf[dt] = *(const short8*)(vcbase + (dt * 16 + nl) * 128 + w * 32 + quad * 8);
        // ---- mask (row nl, this thread's 8 keys) + register max tree ----
        float cmax = -INFINITY;
#pragma unroll
        for (int tt = 0; tt < 2; ++tt)
#pragma unroll
            for (int r = 0; r < 4; ++r) {
                int kp = c * 128 + w * 32 + tt * 16 + quad * 4 + r;
                float s = sacc[tt][r] * SCALEf;
                bool ok = (kp <= mypos) && (amv[tt][r] != 0) &&
                          (((rbrow >> c) & 1u) || (mypos - kp) < WINn);
                s = ok ? s : NEGf;
                sacc[tt][r] = s;
                cmax = fmaxf(cmax, s);
            }
        // wave-local row max: 2 shuffles across quad groups
        cmax = fmaxf(cmax, __shfl_xor(cmax, 16, 64));
        cmax = fmaxf(cmax, __shfl_xor(cmax, 32, 64));
        if (quad == 0) Mb[nl][w] = cmax;
        __syncthreads();
        // ---- global per-row max for rows nl (exp) and quad*4+r (rescale) ----
        float4 mnl4 = *(const float4*)&Mb[nl][0];
        float Mg = fmaxf(fmaxf(mnl4.x, mnl4.y), fmaxf(mnl4.z, mnl4.w));
        float newm = fmaxf(m_nl, Mg);
        float fac_nl = __expf(m_nl - newm);
        m_nl = newm;
        float fac_acc[4];
#pragma unroll
        for (int r = 0; r < 4; ++r) {
            float4 mr4 = *(const float4*)&Mb[quad * 4 + r][0];
            float Mgr = fmaxf(fmaxf(mr4.x, mr4.y), fmaxf(mr4.z, mr4.w));
            float nm = fmaxf(m_acc[r], Mgr);
            fac_acc[r] = __expf(m_acc[r] - nm);
            m_acc[r] = nm;
        }
        // ---- P = exp(s - m), per-thread l update, stash P in LDS ----
        float psum = 0.f;
#pragma unroll
        for (int tt = 0; tt < 2; ++tt) {
            short4v pv;
#pragma unroll
            for (int r = 0; r < 4; ++r) {
                float p = __expf(sacc[tt][r] - m_nl);
                psum += p;
                pv[r] = f2bf(p);
            }
            *(short4v*)&Psh[w][nl][tt * 16 + quad * 4] = pv;
        }
        l_t = l_t * fac_nl + psum;
        // ---- rescale O, PV MFMAs ----
#pragma unroll
        for (int dt = 0; dt < 8; ++dt)
#pragma unroll
            for (int r = 0; r < 4; ++r) oacc[dt][r] *= fac_acc[r];
        short8 pf = *(const short8*)&Psh[w][nl][quad * 8];
#pragma unroll
        for (int dt = 0; dt < 8; ++dt)
            oacc[dt] = __builtin_amdgcn_mfma_f32_16x16x32_bf16(pf, vf[dt], oacc[dt], 0, 0, 0);
        __syncthreads();   // Psh/Mb reuse next chunk; keeps waves chunk-aligned
    }
    // ---- final l reduction: per-thread partials -> per-row wave sums ----
    l_t += __shfl_xor(l_t, 16, 64);
    l_t += __shfl_xor(l_t, 32, 64);
    if (quad == 0) Lb[nl][w] = l_t;
    // ---- merge: all waves share the m sequence -> O_total = sum partial O ----
    if (par == 0) {
#pragma unroll
        for (int dt = 0; dt < 8; ++dt)
#pragma unroll
            for (int r = 0; r < 4; ++r)
                Ob[dt][quad * 4 + r][nl] = oacc[dt][r];
    }
    __syncthreads();
    if (par == 1) {
#pragma unroll
        for (int dt = 0; dt < 8; ++dt)
#pragma unroll
            for (int r = 0; r < 4; ++r)
                Ob[dt][quad * 4 + r][nl] += oacc[dt][r];
    }
    __syncthreads();
    if (par == 2) {
#pragma unroll
        for (int dt = 0; dt < 8; ++dt)
#pragma unroll
            for (int r = 0; r < 4; ++r)
                Ob[dt][quad * 4 + r][nl] += oacc[dt][r];
    }
    __syncthreads();
    if (par == 3) {
#pragma unroll
        for (int dt = 0; dt < 8; ++dt)
#pragma unroll
            for (int r = 0; r < 4; ++r)
                Ob[dt][quad * 4 + r][nl] += oacc[dt][r];
    }
    __syncthreads();
    float Linv[4];
#pragma unroll
    for (int r = 0; r < 4; ++r) {
        float4 l4 = *(const float4*)&Lb[quad * 4 + r][0];
        Linv[r] = 1.0f / ((l4.x + l4.y) + (l4.z + l4.w));
    }
#pragma unroll
    for (int j = 0; j < 2; ++j) {
        int dt = par * 2 + j;
#pragma unroll
        for (int r = 0; r < 4; ++r) {
            int row = quad * 4 + r;
            float val = Ob[dt][row][nl] * Linv[r];
            size_t off = (size_t)(r0 + row) * 2048 + h * 128 + dt * 16 + nl;
            qbuf[off] = val;
            ab[off] = f2bf(val);
        }
    }
}

extern "C" void kernel_launch(void* const* d_in, const int* in_sizes, int n_in,
                              void* d_out, int out_size, void* d_ws, size_t ws_size,
                              hipStream_t stream) {
    const float* hs   = (const float*)d_in[0];
    const float* cosb = (const float*)d_in[1];
    const float* sinb = (const float*)d_in[2];
    const int*   am   = (const int*)d_in[3];
    const float* Wq = (const float*)d_in[5];
    const float* bq = (const float*)d_in[6];
    const float* Wk = (const float*)d_in[7];
    const float* bk = (const float*)d_in[8];
    const float* Wv = (const float*)d_in[9];
    const float* bv = (const float*)d_in[10];
    const float* Wo = (const float*)d_in[11];
    float* out = (float*)d_out;

    float* qbuf = (float*)d_ws;                       // 4,194,304 f
    float* kbuf = qbuf + (size_t)Sn * HIDn;           // 524,288 f
    float* vbuf = kbuf + (size_t)Sn * HKVn * HDn;     // 524,288 f
    float* kcm  = vbuf + (size_t)Sn * HKVn * HDn;     // 4096 f
    float* kcx  = kcm + 4096;                         // 4096 f
    unsigned int* mask32 = (unsigned int*)(kcx + 4096);  // 4096 u32
    int* flags = (int*)(mask32 + 4096);               // 4096 i32
    short* kb  = (short*)(flags + 4096);              // 524,288 s
    short* vtb = kb + (size_t)HKVn * Sn * HDn;        // 524,288 s
    char* P = (char*)(vtb + (size_t)HKVn * Sn * HDn);
    const size_t WSZ = (size_t)HIDn * HIDn * sizeof(short);   // 8,388,608 B
    const size_t HSZ = (size_t)Sn * HIDn * sizeof(short);     // 8,388,608 B
    const size_t WVSZ = (size_t)(HKVn * HDn) * HIDn * sizeof(short); // 1 MB
    size_t base = (size_t)((char*)P - (char*)d_ws);
    bool big  = ws_size >= base + 2 * WSZ;
    bool big2 = ws_size >= base + 2 * WSZ + 2 * HSZ + WVSZ;

    dim3 blk(256);
    if (big2) {
        short* W1 = (short*)P;              // Wq hi^T; later qfix; later Wo^T
        short* W2 = (short*)(P + WSZ);      // Wq lo^T; later ab
        short* ab = W2;
        float* qfix = (float*)W1;
        short* hshi = (short*)(P + 2 * WSZ);
        short* hslo = hshi + (size_t)Sn * HIDn;
        short* WvT  = hslo + (size_t)Sn * HIDn;
        // hs -> bf16 hi/lo once (kills per-tile reconversion in Q/V proj)
        split_hs<<<(Sn * HIDn / 4) / 256, blk, 0, stream>>>(hs, hshi, hslo);
        trans_split<<<dim3(64, 64), blk, 0, stream>>>(Wq, W1, W2, HIDn, HIDn);
        // Q proj: split-K=4 -> 1024 blocks (was 256 = 1/CU barrier-bound)
        hipMemsetAsync(qbuf, 0, (size_t)Sn * HIDn * sizeof(float), stream);
        gemm_mfma<3, false, true><<<dim3(16, 16, 4), blk, 0, stream>>>(
            hshi, hslo, W1, W2, bq, qbuf, nullptr, Sn, HIDn, HIDn);
        // K proj: exact fp32 split-K (selection stats need fp32 K)
        hipMemsetAsync(kbuf, 0, (size_t)Sn * HKVn * HDn * sizeof(float), stream);
        kproj_splitk<<<dim3((HKVn * HDn) / 64, Sn / 64, 8), blk, 0, stream>>>(
            hs, Wk, bk, kbuf, Sn, HKVn * HDn, HIDn, HIDn / 8);
        // V proj: split-K=8 -> 256 blocks (was 32), fp32 atomic, then transpose
        trans_split<<<dim3(8, 64), blk, 0, stream>>>(Wv, WvT, nullptr, HIDn, HKVn * HDn);
        hipMemsetAsync(vbuf, 0, (size_t)Sn * HKVn * HDn * sizeof(float), stream);
        gemm_mfma<0, false, true><<<dim3(2, 16, 8), blk, 0, stream>>>(
            hshi, nullptr, WvT, nullptr, bv, vbuf, nullptr, Sn, HKVn * HDn, HIDn);
        conv_v<<<(Sn * 256) / 256, blk, 0, stream>>>(vbuf, vtb);
        rope_kernel<<<(Sn * 18 * 64) / 256, blk, 0, stream>>>(qbuf, kbuf, cosb, sinb, kb);
        chunk_stats<<<HKVn * Ncn, 512, 0, stream>>>(kbuf, kcm, kcx, flags);
        block_scores<<<dim3(Sn, HKVn), 128, 0, stream>>>(qbuf, kcm, kcx, mask32, flags);
        fixup_q<<<2048, blk, 0, stream>>>(hs, Wq, bq, cosb, sinb, flags, qfix);
        fixup_sel<<<FLAGCAP, 128, 0, stream>>>(qfix, kcm, kcx, flags, mask32);
        attn_mfma<<<dim3(Sn / 16, HQn), blk, 0, stream>>>(qbuf, kb, vtb, mask32, am, ab);
        // O proj: split-K=4 -> 1024 blocks
        trans_split<<<dim3(64, 64), blk, 0, stream>>>(Wo, W1, nullptr, HIDn, HIDn);
        hipMemsetAsync(out, 0, (size_t)Sn * HIDn * sizeof(float), stream);
        gemm_mfma<0, false, true><<<dim3(16, 16, 4), blk, 0, stream>>>(
            ab, nullptr, W1, nullptr, nullptr, out, nullptr, Sn, HIDn, HIDn);
    } else if (big) {
        short* W1 = (short*)P;
        short* W2 = (short*)(P + WSZ);
        short* ab = W2;
        float* qfix = (float*)W1;
        short* WvT = (short*)vbuf;
        trans_split<<<dim3(64, 64), blk, 0, stream>>>(Wq, W1, W2, HIDn, HIDn);
        gemm_mfma<1, false, false><<<dim3(16, 16), blk, 0, stream>>>(hs, nullptr, W1, W2, bq, qbuf, nullptr, Sn, HIDn, HIDn);
        hipMemsetAsync(kbuf, 0, (size_t)Sn * HKVn * HDn * sizeof(float), stream);
        kproj_splitk<<<dim3((HKVn * HDn) / 64, Sn / 64, 8), blk, 0, stream>>>(
            hs, Wk, bk, kbuf, Sn, HKVn * HDn, HIDn, HIDn / 8);
        trans_split<<<dim3(8, 64), blk, 0, stream>>>(Wv, WvT, nullptr, HIDn, HKVn * HDn);
        gemm_mfma<2, true, false><<<dim3(2, 16), blk, 0, stream>>>(hs, nullptr, WvT, nullptr, bv, nullptr, vtb, Sn, HKVn * HDn, HIDn);
        rope_kernel<<<(Sn * 18 * 64) / 256, blk, 0, stream>>>(qbuf, kbuf, cosb, sinb, kb);
        chunk_stats<<<HKVn * Ncn, 512, 0, stream>>>(kbuf, kcm, kcx, flags);
        block_scores<<<dim3(Sn, HKVn), 128, 0, stream>>>(qbuf, kcm, kcx, mask32, flags);
        fixup_q<<<2048, blk, 0, stream>>>(hs, Wq, bq, cosb, sinb, flags, qfix);
        fixup_sel<<<FLAGCAP, 128, 0, stream>>>(qfix, kcm, kcx, flags, mask32);
        attn_mfma<<<dim3(Sn / 16, HQn), blk, 0, stream>>>(qbuf, kb, vtb, mask32, am, ab);
        trans_split<<<dim3(64, 64), blk, 0, stream>>>(Wo, W1, nullptr, HIDn, HIDn);
        gemm_mfma<0, false, false><<<dim3(16, 16), blk, 0, stream>>>(ab, nullptr, W1, nullptr, nullptr, out, nullptr, Sn, HIDn, HIDn);
    } else {
        short* ab = (short*)P;
        gemm64<<<dim3(HIDn / 64, Sn / 64), blk, 0, stream>>>(hs, Wq, bq, qbuf, Sn, HIDn, HIDn);
        gemm64<<<dim3((HKVn * HDn) / 64, Sn / 64), blk, 0, stream>>>(hs, Wk, bk, kbuf, Sn, HKVn * HDn, HIDn);
        gemm64<<<dim3((HKVn * HDn) / 64, Sn / 64), blk, 0, stream>>>(hs, Wv, bv, vbuf, Sn, HKVn * HDn, HIDn);
        rope_kernel<<<(Sn * 18 * 64) / 256, blk, 0, stream>>>(qbuf, kbuf, cosb, sinb, kb);
        conv_v<<<(Sn * 256) / 256, blk, 0, stream>>>(vbuf, vtb);
        chunk_stats<<<HKVn * Ncn, 512, 0, stream>>>(kbuf, kcm, kcx, flags);
        block_scores<<<dim3(Sn, HKVn), 128, 0, stream>>>(qbuf, kcm, kcx, mask32, flags);
        attn_mfma<<<dim3(Sn / 16, HQn), blk, 0, stream>>>(qbuf, kb, vtb, mask32, am, ab);
        gemm64<<<dim3(HIDn / 64, Sn / 64), blk, 0, stream>>>(qbuf, Wo, nullptr, out, Sn, HIDn, HIDn);
    }
}

// Round 11
// 693.194 us; speedup vs baseline: 1.1110x; 1.1110x over previous
//
#include <hip/hip_runtime.h>
#include <hip/hip_bf16.h>

#define Sn    2048
#define HIDn  2048
#define HQn   16
#define HKVn  2
#define HDn   128
#define Gn    8
#define CSn   128
#define Ncn   16
#define NBLK  8
#define WINn  16
#define SCALEf 0.08838834764831845f   // 128^-0.5
#define NEGf  (-1.0e9f)
#define ALPHAf 0.8f
#define MIXLf  0.5f
#define EPSGAP 2.0e-3f
#define FLAGCAP 2040

typedef __attribute__((ext_vector_type(8))) short short8;   // 8 bf16 = 4 VGPRs
typedef __attribute__((ext_vector_type(4))) short short4v;
typedef __attribute__((ext_vector_type(4))) float f32x4;
typedef __attribute__((ext_vector_type(4))) int int4v;

static __device__ __forceinline__ short f2bf(float x) {
    union { float f; unsigned u; } v; v.f = x;
    unsigned r = v.u + 0x7fffu + ((v.u >> 16) & 1u);
    return (short)(r >> 16);
}
static __device__ __forceinline__ float bf2f(short b) {
    union { float f; unsigned u; } v; v.u = ((unsigned)(unsigned short)b) << 16;
    return v.f;
}

// ---------------- fp32 GEMM (fallback path only) ----------------
__global__ void gemm64(const float* __restrict__ A, const float* __restrict__ W,
                       const float* __restrict__ bias, float* __restrict__ C,
                       int M, int N, int K) {
    __shared__ float As[16][65];
    __shared__ float Bs[16][65];
    const int tid = threadIdx.x;
    const int tx = tid & 15, ty = tid >> 4;
    const int m0 = blockIdx.y * 64, n0 = blockIdx.x * 64;
    float acc[4][4] = {};
    for (int k0 = 0; k0 < K; k0 += 16) {
#pragma unroll
        for (int r = 0; r < 4; ++r) {
            int flat = tid + 256 * r;
            int am = flat >> 4, ak = flat & 15;
            As[ak][am] = A[(size_t)(m0 + am) * K + k0 + ak];
            int bk = flat >> 6, bn = flat & 63;
            Bs[bk][bn] = W[(size_t)(k0 + bk) * N + n0 + bn];
        }
        __syncthreads();
#pragma unroll
        for (int kk = 0; kk < 16; ++kk) {
            float a[4], b[4];
#pragma unroll
            for (int i = 0; i < 4; ++i) a[i] = As[kk][ty * 4 + i];
#pragma unroll
            for (int j = 0; j < 4; ++j) b[j] = Bs[kk][tx * 4 + j];
#pragma unroll
            for (int i = 0; i < 4; ++i)
#pragma unroll
                for (int j = 0; j < 4; ++j) acc[i][j] += a[i] * b[j];
        }
        __syncthreads();
    }
#pragma unroll
    for (int i = 0; i < 4; ++i)
#pragma unroll
        for (int j = 0; j < 4; ++j) {
            int m = m0 + ty * 4 + i, n = n0 + tx * 4 + j;
            C[(size_t)m * N + n] = acc[i][j] + (bias ? bias[n] : 0.0f);
        }
}

// ---------------- split-K fp32 GEMM for K projection (M=2048,N=256,K=2048) ----
__global__ __launch_bounds__(256) void kproj_splitk(
        const float* __restrict__ A, const float* __restrict__ W,
        const float* __restrict__ bias, float* __restrict__ C,
        int M, int N, int K, int Ks) {
    __shared__ float As[16][68];   // [k][m]
    __shared__ float Bs[16][68];   // [k][n]
    const int tid = threadIdx.x;
    const int tx = tid & 15, ty = tid >> 4;
    const int m0 = blockIdx.y * 64, n0 = blockIdx.x * 64;
    const int kbase = blockIdx.z * Ks;
    const int am = tid >> 2, ac = tid & 3;     // A: row am (64), float4 seg ac (4)
    const int bk = tid >> 4, bc = tid & 15;    // B: row bk (16), float4 seg bc (16)
    float acc[4][4] = {};
    for (int k0 = kbase; k0 < kbase + Ks; k0 += 16) {
        float4 av = *(const float4*)&A[(size_t)(m0 + am) * K + k0 + ac * 4];
        As[ac * 4 + 0][am] = av.x;
        As[ac * 4 + 1][am] = av.y;
        As[ac * 4 + 2][am] = av.z;
        As[ac * 4 + 3][am] = av.w;
        *(float4*)&Bs[bk][bc * 4] =
            *(const float4*)&W[(size_t)(k0 + bk) * N + n0 + bc * 4];
        __syncthreads();
#pragma unroll
        for (int kk = 0; kk < 16; ++kk) {
            float4 a4 = *(const float4*)&As[kk][ty * 4];
            float4 b4 = *(const float4*)&Bs[kk][tx * 4];
            float a[4] = {a4.x, a4.y, a4.z, a4.w};
            float b[4] = {b4.x, b4.y, b4.z, b4.w};
#pragma unroll
            for (int i = 0; i < 4; ++i)
#pragma unroll
                for (int j = 0; j < 4; ++j) acc[i][j] += a[i] * b[j];
        }
        __syncthreads();
    }
    const bool addb = (blockIdx.z == 0) && (bias != nullptr);
#pragma unroll
    for (int i = 0; i < 4; ++i)
#pragma unroll
        for (int j = 0; j < 4; ++j) {
            int m = m0 + ty * 4 + i, n = n0 + tx * 4 + j;
            float v = acc[i][j] + (addb ? bias[n] : 0.0f);
            atomicAdd(&C[(size_t)m * N + n], v);
        }
}

// ---------------- W[K][N] fp32 -> Wt[N][K] bf16 hi (+lo) ----------------
__global__ void trans_split(const float* __restrict__ W, short* __restrict__ Whi,
                            short* __restrict__ Wlo, int K, int N) {
    __shared__ float tl[32][33];
    const int k0 = blockIdx.y * 32, n0 = blockIdx.x * 32;
    const int c = threadIdx.x & 31, r8 = threadIdx.x >> 5;
#pragma unroll
    for (int it = 0; it < 4; ++it) {
        int r = r8 + it * 8;
        tl[r][c] = W[(size_t)(k0 + r) * N + n0 + c];
    }
    __syncthreads();
#pragma unroll
    for (int it = 0; it < 4; ++it) {
        int r = r8 + it * 8;
        float x = tl[c][r];                      // = W[k0+c][n0+r]
        short hi = f2bf(x);
        Whi[(size_t)(n0 + r) * K + k0 + c] = hi;
        if (Wlo) Wlo[(size_t)(n0 + r) * K + k0 + c] = f2bf(x - bf2f(hi));
    }
}

// ---------------- hs fp32 -> bf16 hi/lo (once, removes per-tile reconversion) --
__global__ void split_hs(const float* __restrict__ hs, short* __restrict__ hi,
                         short* __restrict__ lo) {
    int idx = blockIdx.x * blockDim.x + threadIdx.x;   // S*HID/4 float4s
    float4 v = ((const float4*)hs)[idx];
    short4v h, l;
    float x[4] = {v.x, v.y, v.z, v.w};
#pragma unroll
    for (int i = 0; i < 4; ++i) {
        short hh = f2bf(x[i]);
        h[i] = hh;
        l[i] = f2bf(x[i] - bf2f(hh));
    }
    ((short4v*)hi)[idx] = h;
    ((short4v*)lo)[idx] = l;
}

// ---------------- MFMA GEMM: C[M,N] = A[M,K] @ B + bias ----------------
// B transposed bf16 [N][K]. AMODE: 0 = A bf16; 1 = A fp32 split bf16x3 on the
// fly; 2 = A fp32 rounded to bf16 single; 3 = A pre-split bf16 hi/lo (Av=hi,
// Alo2=lo). VOUT: epilogue writes vtb bf16 [kv][c][d][j]. SK: K sliced across
// blockIdx.z, fp32 atomicAdd epilogue (C pre-zeroed), bias added by z==0.
template <int AMODE, bool VOUT, bool SK>
__global__ __launch_bounds__(256) void gemm_mfma(
        const void* __restrict__ Av, const short* __restrict__ Alo2,
        const short* __restrict__ Bhi, const short* __restrict__ Blo,
        const float* __restrict__ bias, float* __restrict__ C,
        short* __restrict__ vout, int M, int N, int K) {
    constexpr bool DUAL = (AMODE == 1 || AMODE == 3);
    __shared__ short Ahs[128][40];
    __shared__ short Bhs[128][40];
    __shared__ short Als[DUAL ? 128 : 1][40];
    __shared__ short Bls[DUAL ? 128 : 1][40];
    const int tid = threadIdx.x;
    const int w = tid >> 6, lane = tid & 63, nl = lane & 15, quad = lane >> 4;
    const int wm = w >> 1, wn = w & 1;
    const int m0 = blockIdx.y * 128, n0 = blockIdx.x * 128;
    const int srow = tid >> 1, sseg = tid & 1;
    f32x4 acc[4][4];
#pragma unroll
    for (int i = 0; i < 4; ++i)
#pragma unroll
        for (int j = 0; j < 4; ++j) acc[i][j] = (f32x4){0.f, 0.f, 0.f, 0.f};

    int kbeg = 0, kend = K;
    if (SK) { int Ks = K / gridDim.z; kbeg = blockIdx.z * Ks; kend = kbeg + Ks; }

    for (int k0 = kbeg; k0 < kend; k0 += 32) {
        if (AMODE == 1 || AMODE == 2) {
            const float* A = (const float*)Av;
            const float* ap = A + (size_t)(m0 + srow) * K + k0 + sseg * 16;
            short8 hi0, hi1, lo0, lo1;
#pragma unroll
            for (int i = 0; i < 8; ++i) {
                float x = ap[i];
                short h = f2bf(x);
                hi0[i] = h; if (AMODE == 1) lo0[i] = f2bf(x - bf2f(h));
            }
#pragma unroll
            for (int i = 0; i < 8; ++i) {
                float x = ap[8 + i];
                short h = f2bf(x);
                hi1[i] = h; if (AMODE == 1) lo1[i] = f2bf(x - bf2f(h));
            }
            *(short8*)&Ahs[srow][sseg * 16] = hi0;
            *(short8*)&Ahs[srow][sseg * 16 + 8] = hi1;
            if (AMODE == 1) {
                *(short8*)&Als[srow][sseg * 16] = lo0;
                *(short8*)&Als[srow][sseg * 16 + 8] = lo1;
            }
        } else {
            const short* A = (const short*)Av;
            const short* ap = A + (size_t)(m0 + srow) * K + k0 + sseg * 16;
            *(short8*)&Ahs[srow][sseg * 16]     = *(const short8*)(ap);
            *(short8*)&Ahs[srow][sseg * 16 + 8] = *(const short8*)(ap + 8);
            if (AMODE == 3) {
                const short* al = Alo2 + (size_t)(m0 + srow) * K + k0 + sseg * 16;
                *(short8*)&Als[srow][sseg * 16]     = *(const short8*)(al);
                *(short8*)&Als[srow][sseg * 16 + 8] = *(const short8*)(al + 8);
            }
        }
        {
            const short* bh = Bhi + (size_t)(n0 + srow) * K + k0 + sseg * 16;
            *(short8*)&Bhs[srow][sseg * 16]     = *(const short8*)(bh);
            *(short8*)&Bhs[srow][sseg * 16 + 8] = *(const short8*)(bh + 8);
        }
        if (DUAL) {
            const short* bl = Blo + (size_t)(n0 + srow) * K + k0 + sseg * 16;
            *(short8*)&Bls[srow][sseg * 16]     = *(const short8*)(bl);
            *(short8*)&Bls[srow][sseg * 16 + 8] = *(const short8*)(bl + 8);
        }
        __syncthreads();
        short8 af[4], bf_[4], al[4], bl_[4];
#pragma unroll
        for (int tm = 0; tm < 4; ++tm)
            af[tm] = *(const short8*)&Ahs[wm * 64 + tm * 16 + nl][quad * 8];
#pragma unroll
        for (int tn = 0; tn < 4; ++tn)
            bf_[tn] = *(const short8*)&Bhs[wn * 64 + tn * 16 + nl][quad * 8];
        if (DUAL) {
#pragma unroll
            for (int tm = 0; tm < 4; ++tm)
                al[tm] = *(const short8*)&Als[wm * 64 + tm * 16 + nl][quad * 8];
#pragma unroll
            for (int tn = 0; tn < 4; ++tn)
                bl_[tn] = *(const short8*)&Bls[wn * 64 + tn * 16 + nl][quad * 8];
        }
#pragma unroll
        for (int tm = 0; tm < 4; ++tm)
#pragma unroll
            for (int tn = 0; tn < 4; ++tn) {
                acc[tm][tn] = __builtin_amdgcn_mfma_f32_16x16x32_bf16(af[tm], bf_[tn], acc[tm][tn], 0, 0, 0);
                if (DUAL) {
                    acc[tm][tn] = __builtin_amdgcn_mfma_f32_16x16x32_bf16(af[tm], bl_[tn], acc[tm][tn], 0, 0, 0);
                    acc[tm][tn] = __builtin_amdgcn_mfma_f32_16x16x32_bf16(al[tm], bf_[tn], acc[tm][tn], 0, 0, 0);
                }
            }
        __syncthreads();
    }
    const bool addb = (bias != nullptr) && (!SK || blockIdx.z == 0);
#pragma unroll
    for (int tm = 0; tm < 4; ++tm)
#pragma unroll
        for (int tn = 0; tn < 4; ++tn)
#pragma unroll
            for (int r = 0; r < 4; ++r) {
                int m = m0 + wm * 64 + tm * 16 + quad * 4 + r;
                int n = n0 + wn * 64 + tn * 16 + nl;
                float v = acc[tm][tn][r] + (addb ? bias[n] : 0.0f);
                if (VOUT) {
                    int kv = n >> 7, d = n & 127, cc = m >> 7, j = m & 127;
                    vout[(((size_t)kv * Ncn + cc) * 128 + d) * 128 + j] = f2bf(v);
                } else if (SK) {
                    atomicAdd(&C[(size_t)m * N + n], v);
                } else {
                    C[(size_t)m * N + n] = v;
                }
            }
}

// ---------------- RoPE in-place on q and k; k also -> bf16 ----------------
__global__ void rope_kernel(float* __restrict__ q, float* __restrict__ k,
                            const float* __restrict__ cosb, const float* __restrict__ sinb,
                            short* __restrict__ kb) {
    int idx = blockIdx.x * blockDim.x + threadIdx.x;   // S*18*64
    int s = idx / (18 * 64);
    int r = idx % (18 * 64);
    int head = r >> 6;
    int d = r & 63;
    float c0 = cosb[s * 128 + d], c1 = cosb[s * 128 + d + 64];
    float s0 = sinb[s * 128 + d], s1 = sinb[s * 128 + d + 64];
    if (head < 16) {
        float* base = q + (size_t)s * 2048 + head * 128;
        float x0 = base[d], x1 = base[d + 64];
        base[d]      = x0 * c0 - x1 * s0;
        base[d + 64] = x1 * c1 + x0 * s1;
    } else {
        int kv = head - 16;
        float* base = k + (size_t)s * 256 + kv * 128;
        float x0 = base[d], x1 = base[d + 64];
        float y0 = x0 * c0 - x1 * s0;
        float y1 = x1 * c1 + x0 * s1;
        base[d] = y0; base[d + 64] = y1;
        short* ko = kb + ((size_t)kv * Sn + s) * 128;
        ko[d] = f2bf(y0); ko[d + 64] = f2bf(y1);
    }
}

// ---------------- V (fp32) -> bf16, transposed per chunk ----------
__global__ void conv_v(const float* __restrict__ v, short* __restrict__ vtb) {
    int idx = blockIdx.x * blockDim.x + threadIdx.x;   // S*256
    int pos = idx >> 8;
    int rem = idx & 255;
    int kv = rem >> 7, d = rem & 127;
    float val = v[(size_t)pos * 256 + kv * 128 + d];
    int c = pos >> 7, j = pos & 127;
    vtb[(((size_t)kv * Ncn + c) * 128 + d) * 128 + j] = f2bf(val);
}

// ---------------- per-chunk K stats (512 thr: 4-way row split + LDS reduce) ----
__global__ void chunk_stats(const float* __restrict__ k, float* __restrict__ kcm,
                            float* __restrict__ kcx, int* __restrict__ flags) {
    if (blockIdx.x == 0 && threadIdx.x == 0) flags[0] = 0;
    int c = blockIdx.x & 15, kv = blockIdx.x >> 4;
    int d = threadIdx.x & 127, part = threadIdx.x >> 7;   // 4 parts x 32 rows
    float sum = 0.f, mx = -INFINITY;
    for (int j = part * 32; j < part * 32 + 32; ++j) {
        float v = k[(size_t)(c * 128 + j) * 256 + kv * 128 + d];
        sum += v; mx = fmaxf(mx, v);
    }
    __shared__ float ssum[4][128];
    __shared__ float smax[4][128];
    ssum[part][d] = sum; smax[part][d] = mx;
    __syncthreads();
    if (threadIdx.x < 128) {
        float s = ssum[0][d] + ssum[1][d] + ssum[2][d] + ssum[3][d];
        float m = fmaxf(fmaxf(smax[0][d], smax[1][d]), fmaxf(smax[2][d], smax[3][d]));
        kcm[(kv * 16 + c) * 128 + d] = s * (1.0f / 128.0f);
        kcx[(kv * 16 + c) * 128 + d] = m;
    }
}

// ---------------- block scores + top-8 -> chunk mask; flag genuine near-ties ----
__global__ void block_scores(const float* __restrict__ q, const float* __restrict__ kcm,
                             const float* __restrict__ kcx, unsigned int* __restrict__ mask32,
                             int* __restrict__ flags) {
    int qpos = blockIdx.x, kv = blockIdx.y;
    int t = threadIdx.x;          // 128: t = c*8 + g
    int c = t >> 3, g = t & 7;
    int h = kv * 8 + g;
    const float* qr = q + (size_t)qpos * 2048 + h * 128;
    const float* km = kcm + (kv * 16 + c) * 128;
    const float* kx = kcx + (kv * 16 + c) * 128;
    float dm = 0.f, dx = 0.f;
#pragma unroll 4
    for (int d = 0; d < 128; ++d) { float qv = qr[d]; dm += qv * km[d]; dx += qv * kx[d]; }
    float sg = (MIXLf * dm + (1.0f - MIXLf) * dx) * SCALEf;
    __shared__ float sh[16][8];
    __shared__ float vals[16];
    sh[c][g] = sg;
    __syncthreads();
    if (t < 16) {
        float mean = 0.f, mxv = -INFINITY;
#pragma unroll
        for (int gg = 0; gg < 8; ++gg) { mean += sh[t][gg]; mxv = fmaxf(mxv, sh[t][gg]); }
        mean *= 0.125f;
        float v = ALPHAf * mean + (1.0f - ALPHAf) * mxv;
        if (t * 128 > qpos) v = NEGf;
        vals[t] = v;
    }
    __syncthreads();
    if (t == 0) {
        unsigned int bits = 0;
        bool taken[16] = {};
        float v8 = -INFINITY;
        for (int it = 0; it < NBLK; ++it) {
            int best = 0; float bv = -INFINITY;
            for (int cc = 0; cc < 16; ++cc)
                if (!taken[cc] && vals[cc] > bv) { bv = vals[cc]; best = cc; }
            taken[best] = true;
            bits |= (1u << best);
            v8 = bv;
        }
        float v9 = -INFINITY;
        for (int cc = 0; cc < 16; ++cc)
            if (!taken[cc] && vals[cc] > v9) v9 = vals[cc];
        int lastc = qpos >> 7;
        unsigned int causal_bits = (1u << (lastc + 1)) - 1u;
        mask32[kv * 2048 + qpos] = bits & causal_bits;
        if (v9 > -0.5e9f && v8 - v9 < EPSGAP) {
            int idx = atomicAdd(flags, 1);
            if (idx < FLAGCAP) flags[1 + idx] = (kv << 16) | qpos;
        }
    }
}

// ---------------- exact fp32 q for flagged rows (parallel) ----------------
__global__ __launch_bounds__(256) void fixup_q(
        const float* __restrict__ hs, const float* __restrict__ Wq,
        const float* __restrict__ bq, const float* __restrict__ cosb,
        const float* __restrict__ sinb, const int* __restrict__ flags,
        float* __restrict__ qfix) {
    int cnt = flags[0]; if (cnt > FLAGCAP) cnt = FLAGCAP;
    const int items = cnt * 8;
    const int tid = threadIdx.x;
    __shared__ float hssh[2048];
    __shared__ float part[2][128];
    __shared__ float qrow[128];
    for (int item = blockIdx.x; item < items; item += gridDim.x) {
        int i = item >> 3, g = item & 7;
        int e = flags[1 + i];
        int kv = e >> 16, qpos = e & 0xffff;
        for (int j = tid; j < 2048; j += 256) hssh[j] = hs[(size_t)qpos * 2048 + j];
        __syncthreads();
        int d = tid & 127, half = tid >> 7;
        int col = (kv * 8 + g) * 128 + d;
        float s0 = 0.f, s1 = 0.f, s2 = 0.f, s3 = 0.f;
        const float* wp = Wq + (size_t)(half * 1024) * 2048 + col;
        const float* hp = hssh + half * 1024;
        for (int k = 0; k < 1024; k += 4) {
            s0 += hp[k + 0] * wp[(size_t)(k + 0) * 2048];
            s1 += hp[k + 1] * wp[(size_t)(k + 1) * 2048];
            s2 += hp[k + 2] * wp[(size_t)(k + 2) * 2048];
            s3 += hp[k + 3] * wp[(size_t)(k + 3) * 2048];
        }
        part[half][d] = (s0 + s1) + (s2 + s3);
        __syncthreads();
        if (tid < 128) qrow[tid] = part[0][tid] + part[1][tid] + bq[col];
        __syncthreads();
        if (tid < 64) {
            int dd = tid;
            float c0 = cosb[qpos * 128 + dd], c1 = cosb[qpos * 128 + dd + 64];
            float s0_ = sinb[qpos * 128 + dd], s1_ = sinb[qpos * 128 + dd + 64];
            float x0 = qrow[dd], x1 = qrow[dd + 64];
            qfix[(size_t)i * 1024 + g * 128 + dd]      = x0 * c0 - x1 * s0_;
            qfix[(size_t)i * 1024 + g * 128 + dd + 64] = x1 * c1 + x0 * s1_;
        }
        __syncthreads();
    }
}

// ---------------- redo top-8 for flagged rows from exact q ----------------
__global__ void fixup_sel(const float* __restrict__ qfix, const float* __restrict__ kcm,
                          const float* __restrict__ kcx, const int* __restrict__ flags,
                          unsigned int* __restrict__ mask32) {
    int cnt = flags[0]; if (cnt > FLAGCAP) cnt = FLAGCAP;
    int i = blockIdx.x;
    if (i >= cnt) return;
    int e = flags[1 + i];
    int kv = e >> 16, qpos = e & 0xffff;
    int t = threadIdx.x;
    int c = t >> 3, g = t & 7;
    const float* qr = qfix + (size_t)i * 1024 + g * 128;
    const float* km = kcm + (kv * 16 + c) * 128;
    const float* kx = kcx + (kv * 16 + c) * 128;
    float dm = 0.f, dx = 0.f;
#pragma unroll 4
    for (int d = 0; d < 128; ++d) { float qv = qr[d]; dm += qv * km[d]; dx += qv * kx[d]; }
    float sg = (MIXLf * dm + (1.0f - MIXLf) * dx) * SCALEf;
    __shared__ float sh[16][8];
    __shared__ float vals[16];
    sh[c][g] = sg;
    __syncthreads();
    if (t < 16) {
        float mean = 0.f, mxv = -INFINITY;
#pragma unroll
        for (int gg = 0; gg < 8; ++gg) { mean += sh[t][gg]; mxv = fmaxf(mxv, sh[t][gg]); }
        mean *= 0.125f;
        float v = ALPHAf * mean + (1.0f - ALPHAf) * mxv;
        if (t * 128 > qpos) v = NEGf;
        vals[t] = v;
    }
    __syncthreads();
    if (t == 0) {
        unsigned int bits = 0;
        bool taken[16] = {};
        for (int it = 0; it < NBLK; ++it) {
            int best = 0; float bv = -INFINITY;
            for (int cc = 0; cc < 16; ++cc)
                if (!taken[cc] && vals[cc] > bv) { bv = vals[cc]; best = cc; }
            taken[best] = true;
            bits |= (1u << best);
        }
        int lastc = qpos >> 7;
        unsigned int causal_bits = (1u << (lastc + 1)) - 1u;
        mask32[kv * 2048 + qpos] = bits & causal_bits;
    }
}

// ---------------- MFMA flash attention (GQA x2: 2 heads/block, swapped QK) ----
// Block = 16 rows x HEAD-PAIR (2h, 2h+1 — same kv group): 4 waves; wave w owns
// keys [32w, 32w+32). K loads, V loads, mask bits, am, causal/window terms are
// all head-independent -> shared across the pair; QK/PV MFMAs and softmax
// state (m, l, P, O) are duplicated per head. Total chunk-visits HALVE vs the
// 1-head version (the only lever 4 null schedule experiments left standing).
// Swapped QK (mfma(K,Q) -> C[key][q]) keeps softmax nearly register-local.
// Grid (128, 8) = 1024 blocks. Same exact online-softmax algebra as verified
// rounds 8/9 (all waves share the per-row max sequence -> O partials sum).
// Barrier safety: `bits` is block-uniform (mask32[r0..r0+15] OR-reduced within
// each 16-lane group + window/causal terms of r0), so all 4 waves iterate
// identical chunk lists and reach every __syncthreads together.
__global__ __launch_bounds__(256, 2) void attn_mfma(
        float* __restrict__ qbuf, const short* __restrict__ kb,
        const short* __restrict__ vtb, const unsigned int* __restrict__ mask32,
        const int* __restrict__ am, short* __restrict__ ab) {
    __shared__ short Psh[4][2][16][40];
    __shared__ float Mb[2][16][4];    // [head][row][wave] per-chunk partial max
    __shared__ float Lb[2][16][4];    // [head][row][wave] final partial sums
    __shared__ float Ob[2][8][16][17];
    const int tid = threadIdx.x;
    const int w = tid >> 6, lane = tid & 63;
    const int nl = lane & 15, quad = lane >> 4;
    const int h0 = blockIdx.y * 2, kv = h0 >> 3;
    const int par = w;
    const int r0 = ((int)gridDim.x - 1 - (int)blockIdx.x) * 16;

    const int mypos = r0 + nl;                       // this thread's softmax row
    const unsigned rbrow = mask32[kv * Sn + mypos];

    unsigned bits = mask32[kv * Sn + r0 + nl];
#pragma unroll
    for (int off = 1; off < 16; off <<= 1) bits |= __shfl_xor(bits, off, 64);
    int wl = (r0 >= 15) ? ((r0 - 15) >> 7) : 0;
    int wh = (r0 + 15) >> 7;
    for (int c = wl; c <= wh; ++c) bits |= (1u << c);
    const int cmw = (r0 + 15) >> 7;
    bits &= (1u << (cmw + 1)) - 1u;

    short8 qf[2][4];
#pragma unroll
    for (int hh = 0; hh < 2; ++hh) {
        const float* qrow = qbuf + (size_t)(r0 + nl) * 2048 + (h0 + hh) * 128;
#pragma unroll
        for (int ks = 0; ks < 4; ++ks) {
            float4 a = *(const float4*)(qrow + ks * 32 + quad * 8);
            float4 b = *(const float4*)(qrow + ks * 32 + quad * 8 + 4);
            short8 v;
            v[0] = f2bf(a.x); v[1] = f2bf(a.y); v[2] = f2bf(a.z); v[3] = f2bf(a.w);
            v[4] = f2bf(b.x); v[5] = f2bf(b.y); v[6] = f2bf(b.z); v[7] = f2bf(b.w);
            qf[hh][ks] = v;
        }
    }

    f32x4 oacc[2][8];
#pragma unroll
    for (int hh = 0; hh < 2; ++hh)
#pragma unroll
        for (int dt = 0; dt < 8; ++dt) oacc[hh][dt] = (f32x4){0.f, 0.f, 0.f, 0.f};
    float m_nl[2] = {-INFINITY, -INFINITY};          // running max, row nl
    float m_acc[2][4];                               // rows quad*4+r
#pragma unroll
    for (int hh = 0; hh < 2; ++hh)
#pragma unroll
        for (int r = 0; r < 4; ++r) m_acc[hh][r] = -INFINITY;
    float l_t[2] = {0.f, 0.f};                       // per-thread partial sums

    unsigned remb = bits;
    while (remb) {
        const int c = __builtin_ctz(remb);
        remb &= remb - 1;
        const short* kcbase = kb + ((size_t)kv * Sn + c * 128) * 128;
        // ---- K loads (SHARED): this wave's 32 keys x 4 hd-slices ----
        short8 kf[2][4];
#pragma unroll
        for (int tt = 0; tt < 2; ++tt) {
            const short* krow = kcbase + (w * 32 + tt * 16 + nl) * 128;
#pragma unroll
            for (int ks = 0; ks < 4; ++ks)
                kf[tt][ks] = *(const short8*)(krow + ks * 32 + quad * 8);
        }
        int4v amv[2];
#pragma unroll
        for (int tt = 0; tt < 2; ++tt)
            amv[tt] = *(const int4v*)&am[c * 128 + w * 32 + tt * 16 + quad * 4];
        // ---- QK MFMAs SWAPPED, both heads: C[key][q] ----
        f32x4 sacc[2][2];
#pragma unroll
        for (int hh = 0; hh < 2; ++hh)
#pragma unroll
            for (int tt = 0; tt < 2; ++tt) {
                f32x4 a = (f32x4){0.f, 0.f, 0.f, 0.f};
#pragma unroll
                for (int ks = 0; ks < 4; ++ks)
                    a = __builtin_amdgcn_mfma_f32_16x16x32_bf16(kf[tt][ks], qf[hh][ks], a, 0, 0, 0);
                sacc[hh][tt] = a;
            }
        __builtin_amdgcn_sched_barrier(0);
        // ---- V loads (SHARED): 8 d-tiles x this wave's key-slice ----
        short8 vf[8];
        const short* vcbase = vtb + (((size_t)kv * Ncn + c) * 128) * 128;
#pragma unroll
        for (int dt = 0; dt < 8; ++dt)
            vf[dt] = *(const short8*)(vcbase + (dt * 16 + nl) * 128 + w * 32 + quad * 8);
        // ---- mask (computed once, head-independent) + register max trees ----
        float cmax[2] = {-INFINITY, -INFINITY};
#pragma unroll
        for (int tt = 0; tt < 2; ++tt)
#pragma unroll
            for (int r = 0; r < 4; ++r) {
                int kp = c * 128 + w * 32 + tt * 16 + quad * 4 + r;
                bool ok = (kp <= mypos) && (amv[tt][r] != 0) &&
                          (((rbrow >> c) & 1u) || (mypos - kp) < WINn);
#pragma unroll
                for (int hh = 0; hh < 2; ++hh) {
                    float s = sacc[hh][tt][r] * SCALEf;
                    s = ok ? s : NEGf;
                    sacc[hh][tt][r] = s;
                    cmax[hh] = fmaxf(cmax[hh], s);
                }
            }
#pragma unroll
        for (int hh = 0; hh < 2; ++hh) {
            cmax[hh] = fmaxf(cmax[hh], __shfl_xor(cmax[hh], 16, 64));
            cmax[hh] = fmaxf(cmax[hh], __shfl_xor(cmax[hh], 32, 64));
        }
        if (quad == 0) { Mb[0][nl][w] = cmax[0]; Mb[1][nl][w] = cmax[1]; }
        __syncthreads();
        // ---- per-head global row max; P = exp(s-m); rescale O; PV ----
        float fac_acc[2][4];
#pragma unroll
        for (int hh = 0; hh < 2; ++hh) {
            float4 mnl4 = *(const float4*)&Mb[hh][nl][0];
            float Mg = fmaxf(fmaxf(mnl4.x, mnl4.y), fmaxf(mnl4.z, mnl4.w));
            float newm = fmaxf(m_nl[hh], Mg);
            float fac_nl = __expf(m_nl[hh] - newm);
            m_nl[hh] = newm;
#pragma unroll
            for (int r = 0; r < 4; ++r) {
                float4 mr4 = *(const float4*)&Mb[hh][quad * 4 + r][0];
                float Mgr = fmaxf(fmaxf(mr4.x, mr4.y), fmaxf(mr4.z, mr4.w));
                float nm = fmaxf(m_acc[hh][r], Mgr);
                fac_acc[hh][r] = __expf(m_acc[hh][r] - nm);
                m_acc[hh][r] = nm;
            }
            float psum = 0.f;
#pragma unroll
            for (int tt = 0; tt < 2; ++tt) {
                short4v pv;
#pragma unroll
                for (int r = 0; r < 4; ++r) {
                    float p = __expf(sacc[hh][tt][r] - m_nl[hh]);
                    psum += p;
                    pv[r] = f2bf(p);
                }
                *(short4v*)&Psh[w][hh][nl][tt * 16 + quad * 4] = pv;
            }
            l_t[hh] = l_t[hh] * fac_nl + psum;
        }
#pragma unroll
        for (int hh = 0; hh < 2; ++hh)
#pragma unroll
            for (int dt = 0; dt < 8; ++dt)
#pragma unroll
                for (int r = 0; r < 4; ++r) oacc[hh][dt][r] *= fac_acc[hh][r];
#pragma unroll
        for (int hh = 0; hh < 2; ++hh) {
            short8 pf = *(const short8*)&Psh[w][hh][nl][quad * 8];
#pragma unroll
            for (int dt = 0; dt < 8; ++dt)
                oacc[hh][dt] = __builtin_amdgcn_mfma_f32_16x16x32_bf16(pf, vf[dt], oacc[hh][dt], 0, 0, 0);
        }
        __syncthreads();   // Psh/Mb reuse next chunk; keeps waves chunk-aligned
    }
    // ---- final l reduction: per-thread partials -> per-row wave sums ----
#pragma unroll
    for (int hh = 0; hh < 2; ++hh) {
        float lt = l_t[hh];
        lt += __shfl_xor(lt, 16, 64);
        lt += __shfl_xor(lt, 32, 64);
        if (quad == 0) Lb[hh][nl][w] = lt;
    }
    // ---- merge: all waves share the m sequence -> O_total = sum partial O ----
    if (par == 0) {
#pragma unroll
        for (int hh = 0; hh < 2; ++hh)
#pragma unroll
            for (int dt = 0; dt < 8; ++dt)
#pragma unroll
                for (int r = 0; r < 4; ++r)
                    Ob[hh][dt][quad * 4 + r][nl] = oacc[hh][dt][r];
    }
    __syncthreads();
    if (par == 1) {
#pragma unroll
        for (int hh = 0; hh < 2; ++hh)
#pragma unroll
            for (int dt = 0; dt < 8; ++dt)
#pragma unroll
                for (int r = 0; r < 4; ++r)
                    Ob[hh][dt][quad * 4 + r][nl] += oacc[hh][dt][r];
    }
    __syncthreads();
    if (par == 2) {
#pragma unroll
        for (int hh = 0; hh < 2; ++hh)
#pragma unroll
            for (int dt = 0; dt < 8; ++dt)
#pragma unroll
                for (int r = 0; r < 4; ++r)
                    Ob[hh][dt][quad * 4 + r][nl] += oacc[hh][dt][r];
    }
    __syncthreads();
    if (par == 3) {
#pragma unroll
        for (int hh = 0; hh < 2; ++hh)
#pragma unroll
            for (int dt = 0; dt < 8; ++dt)
#pragma unroll
                for (int r = 0; r < 4; ++r)
                    Ob[hh][dt][quad * 4 + r][nl] += oacc[hh][dt][r];
    }
    __syncthreads();
#pragma unroll
    for (int hh = 0; hh < 2; ++hh) {
        float Linv[4];
#pragma unroll
        for (int r = 0; r < 4; ++r) {
            float4 l4 = *(const float4*)&Lb[hh][quad * 4 + r][0];
            Linv[r] = 1.0f / ((l4.x + l4.y) + (l4.z + l4.w));
        }
#pragma unroll
        for (int j = 0; j < 2; ++j) {
            int dt = par * 2 + j;
#pragma unroll
            for (int r = 0; r < 4; ++r) {
                int row = quad * 4 + r;
                float val = Ob[hh][dt][row][nl] * Linv[r];
                size_t off = (size_t)(r0 + row) * 2048 + (h0 + hh) * 128 + dt * 16 + nl;
                qbuf[off] = val;
                ab[off] = f2bf(val);
            }
        }
    }
}

extern "C" void kernel_launch(void* const* d_in, const int* in_sizes, int n_in,
                              void* d_out, int out_size, void* d_ws, size_t ws_size,
                              hipStream_t stream) {
    const float* hs   = (const float*)d_in[0];
    const float* cosb = (const float*)d_in[1];
    const float* sinb = (const float*)d_in[2];
    const int*   am   = (const int*)d_in[3];
    const float* Wq = (const float*)d_in[5];
    const float* bq = (const float*)d_in[6];
    const float* Wk = (const float*)d_in[7];
    const float* bk = (const float*)d_in[8];
    const float* Wv = (const float*)d_in[9];
    const float* bv = (const float*)d_in[10];
    const float* Wo = (const float*)d_in[11];
    float* out = (float*)d_out;

    float* qbuf = (float*)d_ws;                       // 4,194,304 f
    float* kbuf = qbuf + (size_t)Sn * HIDn;           // 524,288 f
    float* vbuf = kbuf + (size_t)Sn * HKVn * HDn;     // 524,288 f
    float* kcm  = vbuf + (size_t)Sn * HKVn * HDn;     // 4096 f
    float* kcx  = kcm + 4096;                         // 4096 f
    unsigned int* mask32 = (unsigned int*)(kcx + 4096);  // 4096 u32
    int* flags = (int*)(mask32 + 4096);               // 4096 i32
    short* kb  = (short*)(flags + 4096);              // 524,288 s
    short* vtb = kb + (size_t)HKVn * Sn * HDn;        // 524,288 s
    char* P = (char*)(vtb + (size_t)HKVn * Sn * HDn);
    const size_t WSZ = (size_t)HIDn * HIDn * sizeof(short);   // 8,388,608 B
    const size_t HSZ = (size_t)Sn * HIDn * sizeof(short);     // 8,388,608 B
    const size_t WVSZ = (size_t)(HKVn * HDn) * HIDn * sizeof(short); // 1 MB
    size_t base = (size_t)((char*)P - (char*)d_ws);
    bool big  = ws_size >= base + 2 * WSZ;
    bool big2 = ws_size >= base + 2 * WSZ + 2 * HSZ + WVSZ;

    dim3 blk(256);
    if (big2) {
        short* W1 = (short*)P;              // Wq hi^T; later qfix; later Wo^T
        short* W2 = (short*)(P + WSZ);      // Wq lo^T; later ab
        short* ab = W2;
        float* qfix = (float*)W1;
        short* hshi = (short*)(P + 2 * WSZ);
        short* hslo = hshi + (size_t)Sn * HIDn;
        short* WvT  = hslo + (size_t)Sn * HIDn;
        // hs -> bf16 hi/lo once (kills per-tile reconversion in Q/V proj)
        split_hs<<<(Sn * HIDn / 4) / 256, blk, 0, stream>>>(hs, hshi, hslo);
        trans_split<<<dim3(64, 64), blk, 0, stream>>>(Wq, W1, W2, HIDn, HIDn);
        // Q proj: split-K=4 -> 1024 blocks (was 256 = 1/CU barrier-bound)
        hipMemsetAsync(qbuf, 0, (size_t)Sn * HIDn * sizeof(float), stream);
        gemm_mfma<3, false, true><<<dim3(16, 16, 4), blk, 0, stream>>>(
            hshi, hslo, W1, W2, bq, qbuf, nullptr, Sn, HIDn, HIDn);
        // K proj: exact fp32 split-K (selection stats need fp32 K)
        hipMemsetAsync(kbuf, 0, (size_t)Sn * HKVn * HDn * sizeof(float), stream);
        kproj_splitk<<<dim3((HKVn * HDn) / 64, Sn / 64, 8), blk, 0, stream>>>(
            hs, Wk, bk, kbuf, Sn, HKVn * HDn, HIDn, HIDn / 8);
        // V proj: split-K=8 -> 256 blocks (was 32), fp32 atomic, then transpose
        trans_split<<<dim3(8, 64), blk, 0, stream>>>(Wv, WvT, nullptr, HIDn, HKVn * HDn);
        hipMemsetAsync(vbuf, 0, (size_t)Sn * HKVn * HDn * sizeof(float), stream);
        gemm_mfma<0, false, true><<<dim3(2, 16, 8), blk, 0, stream>>>(
            hshi, nullptr, WvT, nullptr, bv, vbuf, nullptr, Sn, HKVn * HDn, HIDn);
        conv_v<<<(Sn * 256) / 256, blk, 0, stream>>>(vbuf, vtb);
        rope_kernel<<<(Sn * 18 * 64) / 256, blk, 0, stream>>>(qbuf, kbuf, cosb, sinb, kb);
        chunk_stats<<<HKVn * Ncn, 512, 0, stream>>>(kbuf, kcm, kcx, flags);
        block_scores<<<dim3(Sn, HKVn), 128, 0, stream>>>(qbuf, kcm, kcx, mask32, flags);
        fixup_q<<<2048, blk, 0, stream>>>(hs, Wq, bq, cosb, sinb, flags, qfix);
        fixup_sel<<<FLAGCAP, 128, 0, stream>>>(qfix, kcm, kcx, flags, mask32);
        attn_mfma<<<dim3(Sn / 16, HQn / 2), blk, 0, stream>>>(qbuf, kb, vtb, mask32, am, ab);
        // O proj: split-K=4 -> 1024 blocks
        trans_split<<<dim3(64, 64), blk, 0, stream>>>(Wo, W1, nullptr, HIDn, HIDn);
        hipMemsetAsync(out, 0, (size_t)Sn * HIDn * sizeof(float), stream);
        gemm_mfma<0, false, true><<<dim3(16, 16, 4), blk, 0, stream>>>(
            ab, nullptr, W1, nullptr, nullptr, out, nullptr, Sn, HIDn, HIDn);
    } else if (big) {
        short* W1 = (short*)P;
        short* W2 = (short*)(P + WSZ);
        short* ab = W2;
        float* qfix = (float*)W1;
        short* WvT = (short*)vbuf;
        trans_split<<<dim3(64, 64), blk, 0, stream>>>(Wq, W1, W2, HIDn, HIDn);
        gemm_mfma<1, false, false><<<dim3(16, 16), blk, 0, stream>>>(hs, nullptr, W1, W2, bq, qbuf, nullptr, Sn, HIDn, HIDn);
        hipMemsetAsync(kbuf, 0, (size_t)Sn * HKVn * HDn * sizeof(float), stream);
        kproj_splitk<<<dim3((HKVn * HDn) / 64, Sn / 64, 8), blk, 0, stream>>>(
            hs, Wk, bk, kbuf, Sn, HKVn * HDn, HIDn, HIDn / 8);
        trans_split<<<dim3(8, 64), blk, 0, stream>>>(Wv, WvT, nullptr, HIDn, HKVn * HDn);
        gemm_mfma<2, true, false><<<dim3(2, 16), blk, 0, stream>>>(hs, nullptr, WvT, nullptr, bv, nullptr, vtb, Sn, HKVn * HDn, HIDn);
        rope_kernel<<<(Sn * 18 * 64) / 256, blk, 0, stream>>>(qbuf, kbuf, cosb, sinb, kb);
        chunk_stats<<<HKVn * Ncn, 512, 0, stream>>>(kbuf, kcm, kcx, flags);
        block_scores<<<dim3(Sn, HKVn), 128, 0, stream>>>(qbuf, kcm, kcx, mask32, flags);
        fixup_q<<<2048, blk, 0, stream>>>(hs, Wq, bq, cosb, sinb, flags, qfix);
        fixup_sel<<<FLAGCAP, 128, 0, stream>>>(qfix, kcm, kcx, flags, mask32);
        attn_mfma<<<dim3(Sn / 16, HQn / 2), blk, 0, stream>>>(qbuf, kb, vtb, mask32, am, ab);
        trans_split<<<dim3(64, 64), blk, 0, stream>>>(Wo, W1, nullptr, HIDn, HIDn);
        gemm_mfma<0, false, false><<<dim3(16, 16), blk, 0, stream>>>(ab, nullptr, W1, nullptr, nullptr, out, nullptr, Sn, HIDn, HIDn);
    } else {
        short* ab = (short*)P;
        gemm64<<<dim3(HIDn / 64, Sn / 64), blk, 0, stream>>>(hs, Wq, bq, qbuf, Sn, HIDn, HIDn);
        gemm64<<<dim3((HKVn * HDn) / 64, Sn / 64), blk, 0, stream>>>(hs, Wk, bk, kbuf, Sn, HKVn * HDn, HIDn);
        gemm64<<<dim3((HKVn * HDn) / 64, Sn / 64), blk, 0, stream>>>(hs, Wv, bv, vbuf, Sn, HKVn * HDn, HIDn);
        rope_kernel<<<(Sn * 18 * 64) / 256, blk, 0, stream>>>(qbuf, kbuf, cosb, sinb, kb);
        conv_v<<<(Sn * 256) / 256, blk, 0, stream>>>(vbuf, vtb);
        chunk_stats<<<HKVn * Ncn, 512, 0, stream>>>(kbuf, kcm, kcx, flags);
        block_scores<<<dim3(Sn, HKVn), 128, 0, stream>>>(qbuf, kcm, kcx, mask32, flags);
        attn_mfma<<<dim3(Sn / 16, HQn / 2), blk, 0, stream>>>(qbuf, kb, vtb, mask32, am, ab);
        gemm64<<<dim3(HIDn / 64, Sn / 64), blk, 0, stream>>>(qbuf, Wo, nullptr, out, Sn, HIDn, HIDn);
    }
}